// Round 2
// baseline (176.310 us; speedup 1.0000x reference)
//
#include <hip/hip_runtime.h>
#include <hip/hip_fp16.h>

#define MAIN_BLOCKS 6400
#define BLOCK 256

// Build packed per-atom record: (x, y, z, pack[sigma_f16 | sqrt(eps)_f16])
__global__ void lj_prep_kernel(const float* __restrict__ coords,
                               const float* __restrict__ sigma,
                               const float* __restrict__ eps,
                               float4* __restrict__ table, int n_atoms) {
    int i = blockIdx.x * blockDim.x + threadIdx.x;
    if (i < n_atoms) {
        float x = coords[3 * i + 0];
        float y = coords[3 * i + 1];
        float z = coords[3 * i + 2];
        float s  = sigma[i];
        float se = sqrtf(eps[i]);
        unsigned pack = (unsigned)__half_as_ushort(__float2half(s)) |
                        ((unsigned)__half_as_ushort(__float2half(se)) << 16);
        table[i] = make_float4(x, y, z, __uint_as_float(pack));
    }
}

__device__ __forceinline__ float lj_energy(float4 pi, float4 pj,
                                           float L0, float L1, float L2,
                                           float b0, float b1, float b2,
                                           float c2) {
    float dx = pi.x - pj.x;
    float dy = pi.y - pj.y;
    float dz = pi.z - pj.z;
    float sx = dx * b0; sx -= floorf(sx + 0.5f); dx = sx * L0;
    float sy = dy * b1; sy -= floorf(sy + 0.5f); dy = sy * L1;
    float sz = dz * b2; sz -= floorf(sz + 0.5f); dz = sz * L2;
    float r2 = dx * dx + dy * dy + dz * dz;

    unsigned packi = __float_as_uint(pi.w);
    unsigned packj = __float_as_uint(pj.w);
    float si  = __half2float(__ushort_as_half((unsigned short)(packi & 0xffffu)));
    float sj  = __half2float(__ushort_as_half((unsigned short)(packj & 0xffffu)));
    float sei = __half2float(__ushort_as_half((unsigned short)(packi >> 16)));
    float sej = __half2float(__ushort_as_half((unsigned short)(packj >> 16)));

    float sij   = (si + sj) * 0.5f;
    float epsij = sei * sej;            // sqrt(eps_i)*sqrt(eps_j)
    float ratio = (sij * sij) / r2;     // (sigma_ij/dr)^2
    float t     = ratio * ratio * ratio;
    float e     = 4.0f * epsij * t * (t - 1.0f);
    return (r2 <= c2) ? e : 0.0f;
}

__global__ __launch_bounds__(BLOCK) void lj_main_kernel(
        const int4* __restrict__ pairs4,   // 2 pairs per int4
        const int2* __restrict__ pairs2,   // same memory, pair view (for tail)
        const float4* __restrict__ table,
        const float* __restrict__ box,
        const int* __restrict__ cutoff,
        float* __restrict__ out,
        int n4, int n_pairs) {
    const float L0 = box[0], L1 = box[4], L2 = box[8];
    const float b0 = 1.0f / L0, b1 = 1.0f / L1, b2 = 1.0f / L2;
    const float c  = (float)cutoff[0];
    const float c2 = c * c;

    int tid = blockIdx.x * blockDim.x + threadIdx.x;
    int S = gridDim.x * blockDim.x;

    float acc = 0.0f;
    // 4 pairs per thread per iteration: two coalesced int4 pair-loads and
    // 8 independent gathers issued before any consumption (MLP).
    for (int q = tid; q < n4; q += 2 * S) {
        int qb = q + S;
        bool vb = qb < n4;
        int4 p0 = pairs4[q];
        int4 p1 = vb ? pairs4[qb] : make_int4(0, 0, 0, 0);

        float4 ai0 = table[p0.x];
        float4 aj0 = table[p0.y];
        float4 ai1 = table[p0.z];
        float4 aj1 = table[p0.w];
        float4 ai2 = table[p1.x];
        float4 aj2 = table[p1.y];
        float4 ai3 = table[p1.z];
        float4 aj3 = table[p1.w];

        float e0 = lj_energy(ai0, aj0, L0, L1, L2, b0, b1, b2, c2);
        float e1 = lj_energy(ai1, aj1, L0, L1, L2, b0, b1, b2, c2);
        float e2 = lj_energy(ai2, aj2, L0, L1, L2, b0, b1, b2, c2)
                 + lj_energy(ai3, aj3, L0, L1, L2, b0, b1, b2, c2);
        acc += e0 + e1 + (vb ? e2 : 0.0f);
    }
    // tail: at most one leftover pair if n_pairs is odd
    if (tid == 0 && (n_pairs & 1)) {
        int2 ij = pairs2[n_pairs - 1];
        acc += lj_energy(table[ij.x], table[ij.y], L0, L1, L2, b0, b1, b2, c2);
    }

    // wave (64-lane) reduction
    for (int off = 32; off > 0; off >>= 1)
        acc += __shfl_down(acc, off, 64);

    __shared__ float wsum[BLOCK / 64];
    int lane = threadIdx.x & 63;
    int wid  = threadIdx.x >> 6;
    if (lane == 0) wsum[wid] = acc;
    __syncthreads();
    if (threadIdx.x == 0) {
        float s = 0.0f;
        for (int w = 0; w < BLOCK / 64; w++) s += wsum[w];
        atomicAdd(out, s);
    }
}

extern "C" void kernel_launch(void* const* d_in, const int* in_sizes, int n_in,
                              void* d_out, int out_size, void* d_ws, size_t ws_size,
                              hipStream_t stream) {
    const float* coords = (const float*)d_in[0];
    const int*   pairsi = (const int*)d_in[1];
    const float* box    = (const float*)d_in[2];
    const float* sigma  = (const float*)d_in[3];
    const float* eps    = (const float*)d_in[4];
    const int*   cutoff = (const int*)d_in[5];
    int n_atoms = in_sizes[0] / 3;
    int n_pairs = in_sizes[1] / 2;
    float* out = (float*)d_out;

    float4* table = (float4*)d_ws;

    hipMemsetAsync(d_out, 0, sizeof(float), stream);
    lj_prep_kernel<<<(n_atoms + 255) / 256, 256, 0, stream>>>(
        coords, sigma, eps, table, n_atoms);
    lj_main_kernel<<<MAIN_BLOCKS, BLOCK, 0, stream>>>(
        (const int4*)pairsi, (const int2*)pairsi, table, box, cutoff, out,
        n_pairs / 2, n_pairs);
}

// Round 3
// 160.278 us; speedup vs baseline: 1.1000x; 1.1000x over previous
//
#include <hip/hip_runtime.h>
#include <hip/hip_fp16.h>

#define MAIN_BLOCKS 4096
#define BLOCK 256

// Build packed per-atom record: (x, y, z, pack[sigma_f16 | sqrt(eps)_f16])
__global__ void lj_prep_kernel(const float* __restrict__ coords,
                               const float* __restrict__ sigma,
                               const float* __restrict__ eps,
                               float4* __restrict__ table, int n_atoms) {
    int i = blockIdx.x * blockDim.x + threadIdx.x;
    if (i < n_atoms) {
        float x = coords[3 * i + 0];
        float y = coords[3 * i + 1];
        float z = coords[3 * i + 2];
        float s  = sigma[i];
        float se = sqrtf(eps[i]);
        unsigned pack = (unsigned)__half_as_ushort(__float2half(s)) |
                        ((unsigned)__half_as_ushort(__float2half(se)) << 16);
        table[i] = make_float4(x, y, z, __uint_as_float(pack));
    }
}

// Two L1-bypassing (sc0) 16B gathers issued back-to-back, single drain.
// Table is L2-resident (1.6 MB); sc0 avoids the 64B L1 line fill per
// divergent lane (we only use 16B of it) and the L1 tag thrash.
__device__ __forceinline__ void gather2_sc0(const float4* a0, const float4* a1,
                                            float4& r0, float4& r1) {
    asm volatile("global_load_dwordx4 %0, %2, off sc0\n\t"
                 "global_load_dwordx4 %1, %3, off sc0\n\t"
                 "s_waitcnt vmcnt(0)"
                 : "=&v"(r0), "=&v"(r1)
                 : "v"(a0), "v"(a1));
}

__global__ __launch_bounds__(BLOCK) void lj_main_kernel(
        const int2* __restrict__ pairs,
        const float4* __restrict__ table,
        const float* __restrict__ box,
        const int* __restrict__ cutoff,
        float* __restrict__ out,
        int n_pairs) {
    const float L0 = box[0], L1 = box[4], L2 = box[8];
    const float b0 = 1.0f / L0, b1 = 1.0f / L1, b2 = 1.0f / L2;
    const float c  = (float)cutoff[0];
    const float c2 = c * c;

    float acc = 0.0f;
    int tid = blockIdx.x * blockDim.x + threadIdx.x;
    int stride = gridDim.x * blockDim.x;
    for (int p = tid; p < n_pairs; p += stride) {
        int2 ij = pairs[p];
        float4 pi, pj;
        gather2_sc0(table + ij.x, table + ij.y, pi, pj);

        float dx = pi.x - pj.x;
        float dy = pi.y - pj.y;
        float dz = pi.z - pj.z;
        // minimum image (mirrors reference math exactly)
        float sx = dx * b0; sx -= floorf(sx + 0.5f); dx = sx * L0;
        float sy = dy * b1; sy -= floorf(sy + 0.5f); dy = sy * L1;
        float sz = dz * b2; sz -= floorf(sz + 0.5f); dz = sz * L2;
        float r2 = dx * dx + dy * dy + dz * dz;

        unsigned packi = __float_as_uint(pi.w);
        unsigned packj = __float_as_uint(pj.w);
        float si  = __half2float(__ushort_as_half((unsigned short)(packi & 0xffffu)));
        float sj  = __half2float(__ushort_as_half((unsigned short)(packj & 0xffffu)));
        float sei = __half2float(__ushort_as_half((unsigned short)(packi >> 16)));
        float sej = __half2float(__ushort_as_half((unsigned short)(packj >> 16)));

        float sij   = (si + sj) * 0.5f;
        float epsij = sei * sej;            // sqrt(eps_i)*sqrt(eps_j)
        float ratio = (sij * sij) / r2;     // (sigma_ij/dr)^2
        float t     = ratio * ratio * ratio;
        float e     = 4.0f * epsij * t * (t - 1.0f);
        acc += (r2 <= c2) ? e : 0.0f;
    }

    // wave (64-lane) reduction
    for (int off = 32; off > 0; off >>= 1)
        acc += __shfl_down(acc, off, 64);

    __shared__ float wsum[BLOCK / 64];
    int lane = threadIdx.x & 63;
    int wid  = threadIdx.x >> 6;
    if (lane == 0) wsum[wid] = acc;
    __syncthreads();
    if (threadIdx.x == 0) {
        float s = 0.0f;
        for (int w = 0; w < BLOCK / 64; w++) s += wsum[w];
        atomicAdd(out, s);
    }
}

extern "C" void kernel_launch(void* const* d_in, const int* in_sizes, int n_in,
                              void* d_out, int out_size, void* d_ws, size_t ws_size,
                              hipStream_t stream) {
    const float* coords = (const float*)d_in[0];
    const int2*  pairs  = (const int2*)d_in[1];
    const float* box    = (const float*)d_in[2];
    const float* sigma  = (const float*)d_in[3];
    const float* eps    = (const float*)d_in[4];
    const int*   cutoff = (const int*)d_in[5];
    int n_atoms = in_sizes[0] / 3;
    int n_pairs = in_sizes[1] / 2;
    float* out = (float*)d_out;

    float4* table = (float4*)d_ws;

    hipMemsetAsync(d_out, 0, sizeof(float), stream);
    lj_prep_kernel<<<(n_atoms + 255) / 256, 256, 0, stream>>>(
        coords, sigma, eps, table, n_atoms);
    lj_main_kernel<<<MAIN_BLOCKS, BLOCK, 0, stream>>>(
        pairs, table, box, cutoff, out, n_pairs);
}

// Round 4
// 118.147 us; speedup vs baseline: 1.4923x; 1.3566x over previous
//
#include <hip/hip_runtime.h>
#include <hip/hip_fp16.h>

#define BLOCK 256
#define MAIN_BLOCKS_NOF 4096     // fallback (no-filter) config
#define FBLOCK 1024              // filtered main: 1024 thr, 100KB LDS, 1 block/CU
#define FGRID 512

// Fused prep: packed atom record (x,y,z,[sigma_f16|sqrt(eps)_f16]) + cell id.
// Cell grid 8x8x4 (3+3+2 bits = 1 byte). Cell sizes L/8, L/8, L/4.
__global__ void lj_prep_kernel(const float* __restrict__ coords,
                               const float* __restrict__ sigma,
                               const float* __restrict__ eps,
                               const float* __restrict__ box,
                               float4* __restrict__ table,
                               unsigned char* __restrict__ cellg,
                               int n_atoms) {
    int i = blockIdx.x * blockDim.x + threadIdx.x;
    if (i >= n_atoms) return;
    float x = coords[3 * i + 0];
    float y = coords[3 * i + 1];
    float z = coords[3 * i + 2];
    float s  = sigma[i];
    float se = sqrtf(eps[i]);
    unsigned pack = (unsigned)__half_as_ushort(__float2half(s)) |
                    ((unsigned)__half_as_ushort(__float2half(se)) << 16);
    table[i] = make_float4(x, y, z, __uint_as_float(pack));

    float L0 = box[0], L1 = box[4], L2 = box[8];
    int cx = min((int)(x * (8.0f / L0)), 7); cx = max(cx, 0);
    int cy = min((int)(y * (8.0f / L1)), 7); cy = max(cy, 0);
    int cz = min((int)(z * (4.0f / L2)), 3); cz = max(cz, 0);
    cellg[i] = (unsigned char)(cx | (cy << 3) | (cz << 6));
}

__device__ __forceinline__ float lj_energy(float4 pi, float4 pj,
                                           float L0, float L1, float L2,
                                           float b0, float b1, float b2,
                                           float c2) {
    float dx = pi.x - pj.x;
    float dy = pi.y - pj.y;
    float dz = pi.z - pj.z;
    float sx = dx * b0; sx -= floorf(sx + 0.5f); dx = sx * L0;
    float sy = dy * b1; sy -= floorf(sy + 0.5f); dy = sy * L1;
    float sz = dz * b2; sz -= floorf(sz + 0.5f); dz = sz * L2;
    float r2 = dx * dx + dy * dy + dz * dz;

    unsigned packi = __float_as_uint(pi.w);
    unsigned packj = __float_as_uint(pj.w);
    float si  = __half2float(__ushort_as_half((unsigned short)(packi & 0xffffu)));
    float sj  = __half2float(__ushort_as_half((unsigned short)(packj & 0xffffu)));
    float sei = __half2float(__ushort_as_half((unsigned short)(packi >> 16)));
    float sej = __half2float(__ushort_as_half((unsigned short)(packj >> 16)));

    float sij   = (si + sj) * 0.5f;
    float epsij = sei * sej;            // sqrt(eps_i)*sqrt(eps_j)
    float ratio = (sij * sij) / r2;     // (sigma_ij/dr)^2
    float t     = ratio * ratio * ratio;
    float e     = 4.0f * epsij * t * (t - 1.0f);
    return (r2 <= c2) ? e : 0.0f;
}

// Filtered main: per-atom cell bytes staged in (dynamic) LDS; pairs whose
// cells aren't wrapped-adjacent are discarded before any global gather.
// Filter is conservative (cell size >= cutoff per axis), so survivors get
// the exact reference computation and correctness is unaffected.
__global__ __launch_bounds__(FBLOCK) void lj_main_filtered(
        const int2* __restrict__ pairs,
        const float4* __restrict__ table,
        const unsigned char* __restrict__ cellg,
        const float* __restrict__ box,
        const int* __restrict__ cutoff,
        float* __restrict__ out,
        int n_atoms, int n_pairs) {
    extern __shared__ unsigned char cellLds[];

    // cooperative LDS fill, 16B per thread per iter
    int n16 = n_atoms >> 4;  // n_atoms assumed multiple of 16 (100000 is)
    const uint4* src = (const uint4*)cellg;
    uint4* dst = (uint4*)cellLds;
    for (int k = threadIdx.x; k < n16; k += blockDim.x) dst[k] = src[k];
    for (int k = (n16 << 4) + threadIdx.x; k < n_atoms; k += blockDim.x)
        cellLds[k] = cellg[k];
    __syncthreads();

    const float L0 = box[0], L1 = box[4], L2 = box[8];
    const float b0 = 1.0f / L0, b1 = 1.0f / L1, b2 = 1.0f / L2;
    const float c  = (float)cutoff[0];
    const float c2 = c * c;
    // filter validity: cell sizes must be >= cutoff on every axis
    const bool use_filter = (c <= L0 * 0.125f) && (c <= L1 * 0.125f) &&
                            (c <= L2 * 0.25f);

    float acc = 0.0f;
    int tid = blockIdx.x * blockDim.x + threadIdx.x;
    int stride = gridDim.x * blockDim.x;
    for (int p = tid; p < n_pairs; p += stride) {
        int2 ij = pairs[p];
        unsigned ci = cellLds[ij.x];
        unsigned cj = cellLds[ij.y];
        unsigned dcx = (ci - cj) & 7u;
        unsigned dcy = ((ci >> 3) - (cj >> 3)) & 7u;
        unsigned dcz = ((ci >> 6) - (cj >> 6)) & 3u;
        bool near = (dcx <= 1u || dcx == 7u) &&
                    (dcy <= 1u || dcy == 7u) &&
                    (dcz <= 1u || dcz == 3u);
        if (near || !use_filter) {
            float4 pi = table[ij.x];
            float4 pj = table[ij.y];
            acc += lj_energy(pi, pj, L0, L1, L2, b0, b1, b2, c2);
        }
    }

    // wave (64-lane) reduction
    for (int off = 32; off > 0; off >>= 1)
        acc += __shfl_down(acc, off, 64);

    __shared__ float wsum[FBLOCK / 64];
    int lane = threadIdx.x & 63;
    int wid  = threadIdx.x >> 6;
    if (lane == 0) wsum[wid] = acc;
    __syncthreads();
    if (threadIdx.x == 0) {
        float s = 0.0f;
        for (int w = 0; w < FBLOCK / 64; w++) s += wsum[w];
        atomicAdd(out, s);
    }
}

// Fallback main (R1 structure) if workspace is too small for the cell table.
__global__ __launch_bounds__(BLOCK) void lj_main_kernel(
        const int2* __restrict__ pairs,
        const float4* __restrict__ table,
        const float* __restrict__ box,
        const int* __restrict__ cutoff,
        float* __restrict__ out,
        int n_pairs) {
    const float L0 = box[0], L1 = box[4], L2 = box[8];
    const float b0 = 1.0f / L0, b1 = 1.0f / L1, b2 = 1.0f / L2;
    const float c  = (float)cutoff[0];
    const float c2 = c * c;

    float acc = 0.0f;
    int tid = blockIdx.x * blockDim.x + threadIdx.x;
    int stride = gridDim.x * blockDim.x;
    for (int p = tid; p < n_pairs; p += stride) {
        int2 ij = pairs[p];
        float4 pi = table[ij.x];
        float4 pj = table[ij.y];
        acc += lj_energy(pi, pj, L0, L1, L2, b0, b1, b2, c2);
    }
    for (int off = 32; off > 0; off >>= 1)
        acc += __shfl_down(acc, off, 64);
    __shared__ float wsum[BLOCK / 64];
    int lane = threadIdx.x & 63;
    int wid  = threadIdx.x >> 6;
    if (lane == 0) wsum[wid] = acc;
    __syncthreads();
    if (threadIdx.x == 0) {
        float s = 0.0f;
        for (int w = 0; w < BLOCK / 64; w++) s += wsum[w];
        atomicAdd(out, s);
    }
}

extern "C" void kernel_launch(void* const* d_in, const int* in_sizes, int n_in,
                              void* d_out, int out_size, void* d_ws, size_t ws_size,
                              hipStream_t stream) {
    const float* coords = (const float*)d_in[0];
    const int2*  pairs  = (const int2*)d_in[1];
    const float* box    = (const float*)d_in[2];
    const float* sigma  = (const float*)d_in[3];
    const float* eps    = (const float*)d_in[4];
    const int*   cutoff = (const int*)d_in[5];
    int n_atoms = in_sizes[0] / 3;
    int n_pairs = in_sizes[1] / 2;
    float* out = (float*)d_out;

    size_t table_bytes = ((size_t)n_atoms * sizeof(float4) + 255) & ~(size_t)255;
    size_t cell_bytes  = (size_t)n_atoms;
    float4* table = (float4*)d_ws;
    unsigned char* cellg = (unsigned char*)d_ws + table_bytes;

    hipMemsetAsync(d_out, 0, sizeof(float), stream);

    bool can_filter = (ws_size >= table_bytes + cell_bytes) &&
                      (n_atoms <= 160000);  // LDS capacity for cell bytes

    if (can_filter) {
        lj_prep_kernel<<<(n_atoms + 255) / 256, 256, 0, stream>>>(
            coords, sigma, eps, box, table, cellg, n_atoms);
        static bool attr_set = false;  // idempotent; same value every call
        if (!attr_set) {
            hipFuncSetAttribute((const void*)lj_main_filtered,
                                hipFuncAttributeMaxDynamicSharedMemorySize,
                                n_atoms);
            attr_set = true;
        }
        lj_main_filtered<<<FGRID, FBLOCK, n_atoms, stream>>>(
            pairs, table, cellg, box, cutoff, out, n_atoms, n_pairs);
    } else {
        lj_prep_kernel<<<(n_atoms + 255) / 256, 256, 0, stream>>>(
            coords, sigma, eps, box, table, cellg, n_atoms);
        lj_main_kernel<<<MAIN_BLOCKS_NOF, BLOCK, 0, stream>>>(
            pairs, table, box, cutoff, out, n_pairs);
    }
}

// Round 5
// 107.212 us; speedup vs baseline: 1.6445x; 1.1020x over previous
//
#include <hip/hip_runtime.h>
#include <hip/hip_fp16.h>

#define BLOCK 256
#define MAIN_BLOCKS_NOF 4096     // fallback (no-filter) config
#define FBLOCK 1024              // filtered main: 1024 thr, 1 block/CU
#define FGRID 256                // exactly one block per CU
#define NWAVES (FBLOCK / 64)
#define QCAP 128                 // per-wave survivor queue (int2 entries)

// Fused prep: packed atom record (x,y,z,[sigma_f16|sqrt(eps)_f16]) + cell id.
// Cell grid 8x8x4 (3+3+2 bits = 1 byte). Cell sizes L/8, L/8, L/4.
__global__ void lj_prep_kernel(const float* __restrict__ coords,
                               const float* __restrict__ sigma,
                               const float* __restrict__ eps,
                               const float* __restrict__ box,
                               float4* __restrict__ table,
                               unsigned char* __restrict__ cellg,
                               int n_atoms) {
    int i = blockIdx.x * blockDim.x + threadIdx.x;
    if (i >= n_atoms) return;
    float x = coords[3 * i + 0];
    float y = coords[3 * i + 1];
    float z = coords[3 * i + 2];
    float s  = sigma[i];
    float se = sqrtf(eps[i]);
    unsigned pack = (unsigned)__half_as_ushort(__float2half(s)) |
                    ((unsigned)__half_as_ushort(__float2half(se)) << 16);
    table[i] = make_float4(x, y, z, __uint_as_float(pack));

    float L0 = box[0], L1 = box[4], L2 = box[8];
    int cx = min((int)(x * (8.0f / L0)), 7); cx = max(cx, 0);
    int cy = min((int)(y * (8.0f / L1)), 7); cy = max(cy, 0);
    int cz = min((int)(z * (4.0f / L2)), 3); cz = max(cz, 0);
    cellg[i] = (unsigned char)(cx | (cy << 3) | (cz << 6));
}

__device__ __forceinline__ float lj_energy(float4 pi, float4 pj,
                                           float L0, float L1, float L2,
                                           float b0, float b1, float b2,
                                           float c2) {
    float dx = pi.x - pj.x;
    float dy = pi.y - pj.y;
    float dz = pi.z - pj.z;
    float sx = dx * b0; sx -= floorf(sx + 0.5f); dx = sx * L0;
    float sy = dy * b1; sy -= floorf(sy + 0.5f); dy = sy * L1;
    float sz = dz * b2; sz -= floorf(sz + 0.5f); dz = sz * L2;
    float r2 = dx * dx + dy * dy + dz * dz;

    unsigned packi = __float_as_uint(pi.w);
    unsigned packj = __float_as_uint(pj.w);
    float si  = __half2float(__ushort_as_half((unsigned short)(packi & 0xffffu)));
    float sj  = __half2float(__ushort_as_half((unsigned short)(packj & 0xffffu)));
    float sei = __half2float(__ushort_as_half((unsigned short)(packi >> 16)));
    float sej = __half2float(__ushort_as_half((unsigned short)(packj >> 16)));

    float sij   = (si + sj) * 0.5f;
    float epsij = sei * sej;            // sqrt(eps_i)*sqrt(eps_j)
    float ratio = (sij * sij) / r2;     // (sigma_ij/dr)^2
    float t     = ratio * ratio * ratio;
    float e     = 4.0f * epsij * t * (t - 1.0f);
    return (r2 <= c2) ? e : 0.0f;
}

// Filtered + compacted main:
//  - per-atom cell bytes staged in dynamic LDS (conservative adjacency filter)
//  - surviving (i,j) compacted via ballot into a per-wave LDS queue
//  - queue drained 64-at-a-time: gathers + LJ math run at FULL lane density
//  - pair stream software-prefetched one chunk ahead
__global__ __launch_bounds__(FBLOCK) void lj_main_filtered(
        const int2* __restrict__ pairs,
        const float4* __restrict__ table,
        const unsigned char* __restrict__ cellg,
        const float* __restrict__ box,
        const int* __restrict__ cutoff,
        float* __restrict__ out,
        int n_atoms, int n_pairs, int qoff) {
    extern __shared__ unsigned char lds[];
    unsigned char* cellLds = lds;
    int lane = threadIdx.x & 63;
    int wid  = threadIdx.x >> 6;
    int2* queue = (int2*)(lds + qoff) + wid * QCAP;

    // cooperative LDS fill of cell bytes, 16B per thread per iter
    int n16 = n_atoms >> 4;
    const uint4* src = (const uint4*)cellg;
    uint4* dst = (uint4*)cellLds;
    for (int k = threadIdx.x; k < n16; k += blockDim.x) dst[k] = src[k];
    for (int k = (n16 << 4) + threadIdx.x; k < n_atoms; k += blockDim.x)
        cellLds[k] = cellg[k];
    __syncthreads();

    const float L0 = box[0], L1 = box[4], L2 = box[8];
    const float b0 = 1.0f / L0, b1 = 1.0f / L1, b2 = 1.0f / L2;
    const float c  = (float)cutoff[0];
    const float c2 = c * c;
    // filter validity: cell sizes must be >= cutoff on every axis
    const bool use_filter = (c <= L0 * 0.125f) && (c <= L1 * 0.125f) &&
                            (c <= L2 * 0.25f);

    float acc = 0.0f;
    int qcount = 0;

    long base = ((long)blockIdx.x * NWAVES + wid) * 64;
    long step = (long)gridDim.x * NWAVES * 64;

    bool v = (base + lane) < n_pairs;
    int2 ij = v ? pairs[base + lane] : make_int2(0, 0);

    while (base < n_pairs) {
        // prefetch next chunk (hides pair-stream HBM latency)
        long nbase = base + step;
        bool vn = (nbase + lane) < n_pairs;
        int2 ijn = vn ? pairs[nbase + lane] : make_int2(0, 0);

        // conservative cell-adjacency filter (LDS byte reads)
        unsigned ci = cellLds[ij.x];
        unsigned cj = cellLds[ij.y];
        unsigned dcx = (ci - cj) & 7u;
        unsigned dcy = ((ci >> 3) - (cj >> 3)) & 7u;
        unsigned dcz = ((ci >> 6) - (cj >> 6)) & 3u;
        bool near = v && (!use_filter ||
                          ((dcx <= 1u || dcx == 7u) &&
                           (dcy <= 1u || dcy == 7u) &&
                           (dcz <= 1u || dcz == 3u)));

        // wave compaction into per-wave queue
        unsigned long long bal = __ballot(near);
        int pos = (int)__popcll(bal & ((1ull << lane) - 1ull));
        if (near) queue[qcount + pos] = ij;
        qcount += (int)__popcll(bal);

        if (qcount >= 64) {   // wave-uniform branch
            int2 e = queue[lane];
            float4 pi = table[e.x];
            float4 pj = table[e.y];
            acc += lj_energy(pi, pj, L0, L1, L2, b0, b1, b2, c2);
            qcount -= 64;
            if (lane < qcount) {        // slide remainder down
                int2 t = queue[64 + lane];
                queue[lane] = t;
            }
        }

        base = nbase; ij = ijn; v = vn;
    }
    // drain
    if (lane < qcount) {
        int2 e = queue[lane];
        float4 pi = table[e.x];
        float4 pj = table[e.y];
        acc += lj_energy(pi, pj, L0, L1, L2, b0, b1, b2, c2);
    }

    // wave (64-lane) reduction
    for (int off = 32; off > 0; off >>= 1)
        acc += __shfl_down(acc, off, 64);

    __shared__ float wsum[NWAVES];
    if (lane == 0) wsum[wid] = acc;
    __syncthreads();
    if (threadIdx.x == 0) {
        float s = 0.0f;
        for (int w = 0; w < NWAVES; w++) s += wsum[w];
        atomicAdd(out, s);
    }
}

// Fallback main (R1 structure) if workspace/LDS can't hold the tables.
__global__ __launch_bounds__(BLOCK) void lj_main_kernel(
        const int2* __restrict__ pairs,
        const float4* __restrict__ table,
        const float* __restrict__ box,
        const int* __restrict__ cutoff,
        float* __restrict__ out,
        int n_pairs) {
    const float L0 = box[0], L1 = box[4], L2 = box[8];
    const float b0 = 1.0f / L0, b1 = 1.0f / L1, b2 = 1.0f / L2;
    const float c  = (float)cutoff[0];
    const float c2 = c * c;

    float acc = 0.0f;
    int tid = blockIdx.x * blockDim.x + threadIdx.x;
    int stride = gridDim.x * blockDim.x;
    for (int p = tid; p < n_pairs; p += stride) {
        int2 ij = pairs[p];
        float4 pi = table[ij.x];
        float4 pj = table[ij.y];
        acc += lj_energy(pi, pj, L0, L1, L2, b0, b1, b2, c2);
    }
    for (int off = 32; off > 0; off >>= 1)
        acc += __shfl_down(acc, off, 64);
    __shared__ float wsum[BLOCK / 64];
    int lane = threadIdx.x & 63;
    int wid  = threadIdx.x >> 6;
    if (lane == 0) wsum[wid] = acc;
    __syncthreads();
    if (threadIdx.x == 0) {
        float s = 0.0f;
        for (int w = 0; w < BLOCK / 64; w++) s += wsum[w];
        atomicAdd(out, s);
    }
}

extern "C" void kernel_launch(void* const* d_in, const int* in_sizes, int n_in,
                              void* d_out, int out_size, void* d_ws, size_t ws_size,
                              hipStream_t stream) {
    const float* coords = (const float*)d_in[0];
    const int2*  pairs  = (const int2*)d_in[1];
    const float* box    = (const float*)d_in[2];
    const float* sigma  = (const float*)d_in[3];
    const float* eps    = (const float*)d_in[4];
    const int*   cutoff = (const int*)d_in[5];
    int n_atoms = in_sizes[0] / 3;
    int n_pairs = in_sizes[1] / 2;
    float* out = (float*)d_out;

    size_t table_bytes = ((size_t)n_atoms * sizeof(float4) + 255) & ~(size_t)255;
    size_t cell_bytes  = (size_t)n_atoms;
    float4* table = (float4*)d_ws;
    unsigned char* cellg = (unsigned char*)d_ws + table_bytes;

    int qoff = (n_atoms + 15) & ~15;
    int shmem = qoff + NWAVES * QCAP * (int)sizeof(int2);

    hipMemsetAsync(d_out, 0, sizeof(float), stream);
    lj_prep_kernel<<<(n_atoms + 255) / 256, 256, 0, stream>>>(
        coords, sigma, eps, box, table, cellg, n_atoms);

    bool can_filter = (ws_size >= table_bytes + cell_bytes) &&
                      (shmem <= 160 * 1024 - 1024);

    if (can_filter) {
        static bool attr_set = false;  // host-side, idempotent, same every call
        if (!attr_set) {
            hipFuncSetAttribute((const void*)lj_main_filtered,
                                hipFuncAttributeMaxDynamicSharedMemorySize,
                                shmem);
            attr_set = true;
        }
        lj_main_filtered<<<FGRID, FBLOCK, shmem, stream>>>(
            pairs, table, cellg, box, cutoff, out, n_atoms, n_pairs, qoff);
    } else {
        lj_main_kernel<<<MAIN_BLOCKS_NOF, BLOCK, 0, stream>>>(
            pairs, table, box, cutoff, out, n_pairs);
    }
}

// Round 6
// 105.387 us; speedup vs baseline: 1.6730x; 1.0173x over previous
//
#include <hip/hip_runtime.h>
#include <hip/hip_fp16.h>

#define BLOCK 256
#define MAIN_BLOCKS_NOF 4096     // fallback (no-filter) config
#define FBLOCK 1024              // filtered main: 1024 thr, 1 block/CU
#define FGRID 256                // exactly one block per CU
#define NWAVES (FBLOCK / 64)
#define QCAP 256                 // per-wave ring queue (int2); must hold 191

// Fused prep: packed atom record (x,y,z,[sigma_f16|sqrt(eps)_f16]) + cell id.
// Cell grid 8x8x4 (3+3+2 bits = 1 byte). Cell sizes L/8, L/8, L/4.
// Also zeroes out[0] (harness poisons d_out before every launch).
__global__ void lj_prep_kernel(const float* __restrict__ coords,
                               const float* __restrict__ sigma,
                               const float* __restrict__ eps,
                               const float* __restrict__ box,
                               float4* __restrict__ table,
                               unsigned char* __restrict__ cellg,
                               float* __restrict__ out,
                               int n_atoms) {
    int i = blockIdx.x * blockDim.x + threadIdx.x;
    if (i == 0) out[0] = 0.0f;   // stream-ordered before main's atomicAdd
    if (i >= n_atoms) return;
    float x = coords[3 * i + 0];
    float y = coords[3 * i + 1];
    float z = coords[3 * i + 2];
    float s  = sigma[i];
    float se = sqrtf(eps[i]);
    unsigned pack = (unsigned)__half_as_ushort(__float2half(s)) |
                    ((unsigned)__half_as_ushort(__float2half(se)) << 16);
    table[i] = make_float4(x, y, z, __uint_as_float(pack));

    float L0 = box[0], L1 = box[4], L2 = box[8];
    int cx = min((int)(x * (8.0f / L0)), 7); cx = max(cx, 0);
    int cy = min((int)(y * (8.0f / L1)), 7); cy = max(cy, 0);
    int cz = min((int)(z * (4.0f / L2)), 3); cz = max(cz, 0);
    cellg[i] = (unsigned char)(cx | (cy << 3) | (cz << 6));
}

__device__ __forceinline__ float lj_energy(float4 pi, float4 pj,
                                           float L0, float L1, float L2,
                                           float b0, float b1, float b2,
                                           float c2) {
    float dx = pi.x - pj.x;
    float dy = pi.y - pj.y;
    float dz = pi.z - pj.z;
    float sx = dx * b0; sx -= floorf(sx + 0.5f); dx = sx * L0;
    float sy = dy * b1; sy -= floorf(sy + 0.5f); dy = sy * L1;
    float sz = dz * b2; sz -= floorf(sz + 0.5f); dz = sz * L2;
    float r2 = dx * dx + dy * dy + dz * dz;

    unsigned packi = __float_as_uint(pi.w);
    unsigned packj = __float_as_uint(pj.w);
    float si  = __half2float(__ushort_as_half((unsigned short)(packi & 0xffffu)));
    float sj  = __half2float(__ushort_as_half((unsigned short)(packj & 0xffffu)));
    float sei = __half2float(__ushort_as_half((unsigned short)(packi >> 16)));
    float sej = __half2float(__ushort_as_half((unsigned short)(packj >> 16)));

    float sij   = (si + sj) * 0.5f;
    float epsij = sei * sej;            // sqrt(eps_i)*sqrt(eps_j)
    float ratio = (sij * sij) / r2;     // (sigma_ij/dr)^2
    float t     = ratio * ratio * ratio;
    float e     = 4.0f * epsij * t * (t - 1.0f);
    return (r2 <= c2) ? e : 0.0f;
}

__device__ __forceinline__ bool cell_near(unsigned ci, unsigned cj) {
    unsigned dcx = (ci - cj) & 7u;
    unsigned dcy = ((ci >> 3) - (cj >> 3)) & 7u;
    unsigned dcz = ((ci >> 6) - (cj >> 6)) & 3u;
    return (dcx <= 1u || dcx == 7u) &&
           (dcy <= 1u || dcy == 7u) &&
           (dcz <= 1u || dcz == 3u);
}

// Filtered + compacted main:
//  - per-atom cell bytes staged in dynamic LDS (conservative adjacency filter)
//  - 2 pairs/thread via int4 loads (16B/lane coalescing), prefetched 1 ahead
//  - survivors compacted via ballot into a per-wave LDS ring queue
//  - queue drained 64-at-a-time: gathers + LJ math at FULL lane density
__global__ __launch_bounds__(FBLOCK) void lj_main_filtered(
        const int4* __restrict__ pairs4,
        const int2* __restrict__ pairs2,
        const float4* __restrict__ table,
        const unsigned char* __restrict__ cellg,
        const float* __restrict__ box,
        const int* __restrict__ cutoff,
        float* __restrict__ out,
        int n_atoms, int n4, int n_pairs, int qoff) {
    extern __shared__ unsigned char lds[];
    unsigned char* cellLds = lds;
    int lane = threadIdx.x & 63;
    int wid  = threadIdx.x >> 6;
    int2* queue = (int2*)(lds + qoff) + wid * QCAP;

    // cooperative LDS fill of cell bytes, 16B per thread per iter
    int n16 = n_atoms >> 4;
    const uint4* src = (const uint4*)cellg;
    uint4* dst = (uint4*)cellLds;
    for (int k = threadIdx.x; k < n16; k += blockDim.x) dst[k] = src[k];
    for (int k = (n16 << 4) + threadIdx.x; k < n_atoms; k += blockDim.x)
        cellLds[k] = cellg[k];
    __syncthreads();

    const float L0 = box[0], L1 = box[4], L2 = box[8];
    const float b0 = 1.0f / L0, b1 = 1.0f / L1, b2 = 1.0f / L2;
    const float c  = (float)cutoff[0];
    const float c2 = c * c;
    // filter validity: cell sizes must be >= cutoff on every axis
    const bool use_filter = (c <= L0 * 0.125f) && (c <= L1 * 0.125f) &&
                            (c <= L2 * 0.25f);

    float acc = 0.0f;
    int qcount = 0, head = 0;

    long base = ((long)blockIdx.x * NWAVES + wid) * 64;   // int4 units
    long step = (long)gridDim.x * NWAVES * 64;

    bool v = (base + lane) < n4;
    int4 pp = v ? pairs4[base + lane] : make_int4(0, 0, 0, 0);

    while (base < n4) {
        // prefetch next chunk (hides pair-stream HBM latency)
        long nbase = base + step;
        bool vn = (nbase + lane) < n4;
        int4 ppn = vn ? pairs4[nbase + lane] : make_int4(0, 0, 0, 0);

        // pair 0
        bool near0 = v && (!use_filter || cell_near(cellLds[pp.x], cellLds[pp.y]));
        unsigned long long bal0 = __ballot(near0);
        int pos0 = (int)__popcll(bal0 & ((1ull << lane) - 1ull));
        if (near0) queue[(head + qcount + pos0) & (QCAP - 1)] = make_int2(pp.x, pp.y);
        qcount += (int)__popcll(bal0);

        // pair 1
        bool near1 = v && (!use_filter || cell_near(cellLds[pp.z], cellLds[pp.w]));
        unsigned long long bal1 = __ballot(near1);
        int pos1 = (int)__popcll(bal1 & ((1ull << lane) - 1ull));
        if (near1) queue[(head + qcount + pos1) & (QCAP - 1)] = make_int2(pp.z, pp.w);
        qcount += (int)__popcll(bal1);

        while (qcount >= 64) {   // wave-uniform
            int2 e = queue[(head + lane) & (QCAP - 1)];
            float4 pi = table[e.x];
            float4 pj = table[e.y];
            acc += lj_energy(pi, pj, L0, L1, L2, b0, b1, b2, c2);
            head = (head + 64) & (QCAP - 1);
            qcount -= 64;
        }

        base = nbase; pp = ppn; v = vn;
    }
    // drain remainder
    if (lane < qcount) {
        int2 e = queue[(head + lane) & (QCAP - 1)];
        float4 pi = table[e.x];
        float4 pj = table[e.y];
        acc += lj_energy(pi, pj, L0, L1, L2, b0, b1, b2, c2);
    }
    // odd tail pair (not covered by int4 view)
    if (blockIdx.x == 0 && threadIdx.x == 0 && (n_pairs & 1)) {
        int2 e = pairs2[n_pairs - 1];
        acc += lj_energy(table[e.x], table[e.y], L0, L1, L2, b0, b1, b2, c2);
    }

    // wave (64-lane) reduction
    for (int off = 32; off > 0; off >>= 1)
        acc += __shfl_down(acc, off, 64);

    __shared__ float wsum[NWAVES];
    if (lane == 0) wsum[wid] = acc;
    __syncthreads();
    if (threadIdx.x == 0) {
        float s = 0.0f;
        for (int w = 0; w < NWAVES; w++) s += wsum[w];
        atomicAdd(out, s);
    }
}

// Fallback main (R1 structure) if workspace/LDS can't hold the tables.
__global__ __launch_bounds__(BLOCK) void lj_main_kernel(
        const int2* __restrict__ pairs,
        const float4* __restrict__ table,
        const float* __restrict__ box,
        const int* __restrict__ cutoff,
        float* __restrict__ out,
        int n_pairs) {
    const float L0 = box[0], L1 = box[4], L2 = box[8];
    const float b0 = 1.0f / L0, b1 = 1.0f / L1, b2 = 1.0f / L2;
    const float c  = (float)cutoff[0];
    const float c2 = c * c;

    float acc = 0.0f;
    int tid = blockIdx.x * blockDim.x + threadIdx.x;
    int stride = gridDim.x * blockDim.x;
    for (int p = tid; p < n_pairs; p += stride) {
        int2 ij = pairs[p];
        float4 pi = table[ij.x];
        float4 pj = table[ij.y];
        acc += lj_energy(pi, pj, L0, L1, L2, b0, b1, b2, c2);
    }
    for (int off = 32; off > 0; off >>= 1)
        acc += __shfl_down(acc, off, 64);
    __shared__ float wsum[BLOCK / 64];
    int lane = threadIdx.x & 63;
    int wid  = threadIdx.x >> 6;
    if (lane == 0) wsum[wid] = acc;
    __syncthreads();
    if (threadIdx.x == 0) {
        float s = 0.0f;
        for (int w = 0; w < BLOCK / 64; w++) s += wsum[w];
        atomicAdd(out, s);
    }
}

extern "C" void kernel_launch(void* const* d_in, const int* in_sizes, int n_in,
                              void* d_out, int out_size, void* d_ws, size_t ws_size,
                              hipStream_t stream) {
    const float* coords = (const float*)d_in[0];
    const int*   pairsi = (const int*)d_in[1];
    const float* box    = (const float*)d_in[2];
    const float* sigma  = (const float*)d_in[3];
    const float* eps    = (const float*)d_in[4];
    const int*   cutoff = (const int*)d_in[5];
    int n_atoms = in_sizes[0] / 3;
    int n_pairs = in_sizes[1] / 2;
    float* out = (float*)d_out;

    size_t table_bytes = ((size_t)n_atoms * sizeof(float4) + 255) & ~(size_t)255;
    size_t cell_bytes  = (size_t)n_atoms;
    float4* table = (float4*)d_ws;
    unsigned char* cellg = (unsigned char*)d_ws + table_bytes;

    int qoff = (n_atoms + 15) & ~15;
    int shmem = qoff + NWAVES * QCAP * (int)sizeof(int2);

    lj_prep_kernel<<<(n_atoms + 255) / 256, 256, 0, stream>>>(
        coords, sigma, eps, box, table, cellg, out, n_atoms);

    bool can_filter = (ws_size >= table_bytes + cell_bytes) &&
                      (shmem <= 160 * 1024 - 1024);

    if (can_filter) {
        static bool attr_set = false;  // host-side, idempotent, same every call
        if (!attr_set) {
            hipFuncSetAttribute((const void*)lj_main_filtered,
                                hipFuncAttributeMaxDynamicSharedMemorySize,
                                shmem);
            attr_set = true;
        }
        lj_main_filtered<<<FGRID, FBLOCK, shmem, stream>>>(
            (const int4*)pairsi, (const int2*)pairsi, table, cellg, box,
            cutoff, out, n_atoms, n_pairs / 2, n_pairs, qoff);
    } else {
        lj_main_kernel<<<MAIN_BLOCKS_NOF, BLOCK, 0, stream>>>(
            (const int2*)pairsi, table, box, cutoff, out, n_pairs);
    }
}